// Round 1
// baseline (412.733 us; speedup 1.0000x reference)
//
#include <hip/hip_runtime.h>
#include <hip/hip_bf16.h>

// GIN: 2x GINConv(eps=0, MLP 2-layer H=64) + global mean pool + linear.
// N=50000 nodes, E=800000 edges, G=2500 graphs, IN_DIM=14 (11 feat + 3 pos).
//
// Pipeline:
//   memset(agg0|agg1|sums|counts)
//   edge1: agg0[dst] += concat(x,pos)[src]          (14-wide, atomics)
//   node1: h1 = relu(relu((h0+agg0)@W1a+b1a)@W1b+b1b)
//   edge2: agg1[dst] += h1[src]                      (64-wide, atomics)
//   node2: h2 = relu(relu((h1+agg1)@W2a+b2a)@W2b+b2b); sums[batch]+=h2; counts[batch]+=1
//   final: out[g] = dot(sums[g],Wlin)/max(counts[g],1) + blin

#define E_PER_BLK1 16   // edges per block in edge1 (16 lanes/edge, 14 used)
#define E_PER_BLK2 4    // edges per block in edge2 (64 lanes/edge)

__global__ __launch_bounds__(256) void gin_edge1(
    const float* __restrict__ x, const float* __restrict__ pos,
    const int* __restrict__ src, const int* __restrict__ dst,
    float* __restrict__ agg0, int E)
{
    int lane = threadIdx.x & 15;           // feature 0..15 (14 used)
    int le   = threadIdx.x >> 4;           // edge slot within block
    int e    = blockIdx.x * E_PER_BLK1 + le;
    if (e < E && lane < 14) {
        int s = src[e];
        int d = dst[e];
        float v = (lane < 11) ? x[s * 11 + lane] : pos[s * 3 + (lane - 11)];
        atomicAdd(&agg0[d * 14 + lane], v);
    }
}

__global__ __launch_bounds__(256) void gin_edge2(
    const float* __restrict__ h1,
    const int* __restrict__ src, const int* __restrict__ dst,
    float* __restrict__ agg1, int E)
{
    int lane = threadIdx.x & 63;
    int le   = threadIdx.x >> 6;
    int e    = blockIdx.x * E_PER_BLK2 + le;
    if (e < E) {
        int s = src[e];
        int d = dst[e];
        float v = h1[s * 64 + lane];       // coalesced 256B row read
        atomicAdd(&agg1[d * 64 + lane], v);
    }
}

// Layer-1 node MLP: input 14-dim, hidden/out 64-dim.
__global__ __launch_bounds__(256) void gin_node1(
    const float* __restrict__ x, const float* __restrict__ pos,
    const float* __restrict__ agg0,
    const float* __restrict__ W1a, const float* __restrict__ b1a,
    const float* __restrict__ W1b, const float* __restrict__ b1b,
    float* __restrict__ h1, int N)
{
    __shared__ float Wa[14 * 64];
    __shared__ float Wb[64 * 64];
    __shared__ float zs[4][14];
    __shared__ float ts[4][64];

    for (int i = threadIdx.x; i < 14 * 64; i += 256) Wa[i] = W1a[i];
    for (int i = threadIdx.x; i < 64 * 64; i += 256) Wb[i] = W1b[i];
    __syncthreads();

    int lane = threadIdx.x & 63;
    int ln   = threadIdx.x >> 6;           // node slot 0..3
    float ba = b1a[lane];
    float bb = b1b[lane];

    for (int base = blockIdx.x * 4; base < N; base += gridDim.x * 4) {
        int i = base + ln;
        if (i < N && lane < 14) {
            float v = (lane < 11) ? x[i * 11 + lane] : pos[i * 3 + (lane - 11)];
            zs[ln][lane] = v + agg0[i * 14 + lane];
        }
        __syncthreads();
        if (i < N) {
            float acc = ba;
#pragma unroll
            for (int k = 0; k < 14; k++) acc += zs[ln][k] * Wa[k * 64 + lane];
            ts[ln][lane] = fmaxf(acc, 0.0f);
        }
        __syncthreads();
        if (i < N) {
            float acc = bb;
#pragma unroll
            for (int k = 0; k < 64; k++) acc += ts[ln][k] * Wb[k * 64 + lane];
            h1[i * 64 + lane] = fmaxf(acc, 0.0f);   // outer relu of layer 1
        }
        __syncthreads();
    }
}

// Layer-2 node MLP + fused mean-pool accumulation.
__global__ __launch_bounds__(256) void gin_node2(
    const float* __restrict__ h1, const float* __restrict__ agg1,
    const float* __restrict__ W2a, const float* __restrict__ b2a,
    const float* __restrict__ W2b, const float* __restrict__ b2b,
    const int* __restrict__ batch,
    float* __restrict__ sums, float* __restrict__ counts, int N)
{
    __shared__ float Wa[64 * 64];
    __shared__ float Wb[64 * 64];
    __shared__ float zs[4][64];
    __shared__ float ts[4][64];

    for (int i = threadIdx.x; i < 64 * 64; i += 256) {
        Wa[i] = W2a[i];
        Wb[i] = W2b[i];
    }
    __syncthreads();

    int lane = threadIdx.x & 63;
    int ln   = threadIdx.x >> 6;
    float ba = b2a[lane];
    float bb = b2b[lane];

    for (int base = blockIdx.x * 4; base < N; base += gridDim.x * 4) {
        int i = base + ln;
        if (i < N) {
            zs[ln][lane] = h1[i * 64 + lane] + agg1[i * 64 + lane];
        }
        __syncthreads();
        if (i < N) {
            float acc = ba;
#pragma unroll
            for (int k = 0; k < 64; k++) acc += zs[ln][k] * Wa[k * 64 + lane];
            ts[ln][lane] = fmaxf(acc, 0.0f);
        }
        __syncthreads();
        if (i < N) {
            float acc = bb;
#pragma unroll
            for (int k = 0; k < 64; k++) acc += ts[ln][k] * Wb[k * 64 + lane];
            float h2 = fmaxf(acc, 0.0f);           // outer relu of layer 2
            int g = batch[i];
            atomicAdd(&sums[g * 64 + lane], h2);
            if (lane == 0) atomicAdd(&counts[g], 1.0f);
        }
        __syncthreads();
    }
}

__global__ __launch_bounds__(256) void gin_final(
    const float* __restrict__ sums, const float* __restrict__ counts,
    const float* __restrict__ Wlin, const float* __restrict__ blin,
    float* __restrict__ out, int G)
{
    int lane = threadIdx.x & 63;
    int g    = blockIdx.x * 4 + (threadIdx.x >> 6);
    if (g < G) {
        float v = sums[g * 64 + lane] * Wlin[lane];
#pragma unroll
        for (int off = 32; off > 0; off >>= 1) v += __shfl_down(v, off, 64);
        if (lane == 0) out[g] = v / fmaxf(counts[g], 1.0f) + blin[0];
    }
}

extern "C" void kernel_launch(void* const* d_in, const int* in_sizes, int n_in,
                              void* d_out, int out_size, void* d_ws, size_t ws_size,
                              hipStream_t stream) {
    const float* x    = (const float*)d_in[0];
    const float* pos  = (const float*)d_in[1];
    const int*   ei   = (const int*)d_in[2];
    const int*   batch= (const int*)d_in[3];
    const float* W1a  = (const float*)d_in[4];
    const float* b1a  = (const float*)d_in[5];
    const float* W1b  = (const float*)d_in[6];
    const float* b1b  = (const float*)d_in[7];
    const float* W2a  = (const float*)d_in[8];
    const float* b2a  = (const float*)d_in[9];
    const float* W2b  = (const float*)d_in[10];
    const float* b2b  = (const float*)d_in[11];
    const float* Wlin = (const float*)d_in[12];
    const float* blin = (const float*)d_in[13];
    float* out = (float*)d_out;

    const int N = in_sizes[0] / 11;     // 50000
    const int E = in_sizes[2] / 2;      // 800000
    const int G = out_size;             // 2500

    const int* src = ei;
    const int* dst = ei + E;

    // Workspace layout (floats): [agg0 | agg1 | sums | counts(+pad) | h1]
    float* ws     = (float*)d_ws;
    size_t o      = 0;
    float* agg0   = ws + o; o += (size_t)N * 14;
    float* agg1   = ws + o; o += (size_t)N * 64;
    float* sums   = ws + o; o += (size_t)G * 64;
    float* counts = ws + o; o += ((size_t)G + 63) & ~(size_t)63;  // padded
    size_t zero_floats = o;
    float* h1     = ws + o;

    // Zero all accumulators in one shot (agg0..counts are contiguous).
    hipMemsetAsync(ws, 0, zero_floats * sizeof(float), stream);

    gin_edge1<<<(E + E_PER_BLK1 - 1) / E_PER_BLK1, 256, 0, stream>>>(
        x, pos, src, dst, agg0, E);

    gin_node1<<<1024, 256, 0, stream>>>(
        x, pos, agg0, W1a, b1a, W1b, b1b, h1, N);

    gin_edge2<<<(E + E_PER_BLK2 - 1) / E_PER_BLK2, 256, 0, stream>>>(
        h1, src, dst, agg1, E);

    gin_node2<<<1024, 256, 0, stream>>>(
        h1, agg1, W2a, b2a, W2b, b2b, batch, sums, counts, N);

    gin_final<<<(G + 3) / 4, 256, 0, stream>>>(
        sums, counts, Wlin, blin, out, G);
}

// Round 2
// 411.411 us; speedup vs baseline: 1.0032x; 1.0032x over previous
//
#include <hip/hip_runtime.h>
#include <hip/hip_bf16.h>

// GIN: 2x GINConv(eps=0, MLP 2-layer H=64) + global mean pool + linear.
// N=50000 nodes, E=800000 edges, G=2500 graphs.
//
// R1 strategy: scatter-atomics (200 MB atomic write-through in edge2, R0
// profile) replaced by CSR-grouped GATHER. Build CSR by dst once per launch
// (histogram -> hierarchical scan -> cursor fill), then each layer is
// "wave per node: register-accumulate neighbor rows -> MLP", fully fused.

__global__ __launch_bounds__(256) void count_deg(
    const int* __restrict__ dst, int* __restrict__ deg, int E)
{
    int e = blockIdx.x * 256 + threadIdx.x;
    if (e < E) atomicAdd(&deg[dst[e]], 1);
}

// Hierarchical exclusive scan over deg[N] -> offs[N]; bsum holds block totals.
__global__ __launch_bounds__(256) void scan1(
    const int* __restrict__ deg, int* __restrict__ offs,
    int* __restrict__ bsum, int N)
{
    __shared__ int wsum[4];
    int i = blockIdx.x * 256 + threadIdx.x;
    int v = (i < N) ? deg[i] : 0;
    int lane = threadIdx.x & 63, w = threadIdx.x >> 6;
    int s = v;
#pragma unroll
    for (int off = 1; off < 64; off <<= 1) {
        int t = __shfl_up(s, off, 64);
        if (lane >= off) s += t;
    }
    if (lane == 63) wsum[w] = s;
    __syncthreads();
    int add = 0;
    for (int j = 0; j < w; j++) add += wsum[j];
    int incl = s + add;
    if (i < N) offs[i] = incl - v;               // in-block exclusive
    if (threadIdx.x == 255) bsum[blockIdx.x] = incl;
}

__global__ __launch_bounds__(256) void scan2(int* __restrict__ bsum, int NB)
{
    __shared__ int wsum[4];
    int i = threadIdx.x;
    int v = (i < NB) ? bsum[i] : 0;
    int lane = threadIdx.x & 63, w = threadIdx.x >> 6;
    int s = v;
#pragma unroll
    for (int off = 1; off < 64; off <<= 1) {
        int t = __shfl_up(s, off, 64);
        if (lane >= off) s += t;
    }
    if (lane == 63) wsum[w] = s;
    __syncthreads();
    int add = 0;
    for (int j = 0; j < w; j++) add += wsum[j];
    int incl = s + add;
    if (i < NB) bsum[i] = incl - v;              // exclusive block offsets
}

__global__ __launch_bounds__(256) void scan3(
    int* __restrict__ offs, const int* __restrict__ bsum,
    int* __restrict__ cursor, int N)
{
    int i = blockIdx.x * 256 + threadIdx.x;
    if (i < N) {
        int o = offs[i] + bsum[blockIdx.x];
        offs[i] = o;
        cursor[i] = o;
    }
}

__global__ __launch_bounds__(256) void fill_csr(
    const int* __restrict__ src, const int* __restrict__ dst,
    int* __restrict__ cursor, int* __restrict__ ssrc, int E)
{
    int e = blockIdx.x * 256 + threadIdx.x;
    if (e < E) {
        int p = atomicAdd(&cursor[dst[e]], 1);
        ssrc[p] = src[e];
    }
}

// Layer 1 fused: gather concat(x,pos)[neighbors] + self, 2-layer MLP -> h1.
// One wave per node; gather uses 4 subgroups x 16 lanes (14 features used).
__global__ __launch_bounds__(256) void gin_fused1(
    const float* __restrict__ x, const float* __restrict__ pos,
    const int* __restrict__ offs, const int* __restrict__ deg,
    const int* __restrict__ ssrc,
    const float* __restrict__ W1a, const float* __restrict__ b1a,
    const float* __restrict__ W1b, const float* __restrict__ b1b,
    float* __restrict__ h1, int N)
{
    __shared__ float Wa[14 * 64];
    __shared__ float Wb[64 * 64];
    __shared__ float zs[4][14];
    __shared__ float ts[4][64];
    for (int i = threadIdx.x; i < 14 * 64; i += 256) Wa[i] = W1a[i];
    for (int i = threadIdx.x; i < 64 * 64; i += 256) Wb[i] = W1b[i];
    __syncthreads();

    int lane = threadIdx.x & 63;
    int ln   = threadIdx.x >> 6;
    int f    = lane & 15, sub = lane >> 4;
    float ba = b1a[lane], bb = b1b[lane];

    for (int base = blockIdx.x * 4; base < N; base += gridDim.x * 4) {
        int i = base + ln;
        float acc = 0.0f;
        if (i < N) {
            int st = offs[i], len = deg[i];
            for (int k = sub; k < len; k += 4) {
                int s = ssrc[st + k];
                if (f < 14)
                    acc += (f < 11) ? x[s * 11 + f] : pos[s * 3 + (f - 11)];
            }
        }
        acc += __shfl_xor(acc, 16, 64);
        acc += __shfl_xor(acc, 32, 64);
        if (i < N && lane < 14) {
            float own = (lane < 11) ? x[i * 11 + lane] : pos[i * 3 + (lane - 11)];
            zs[ln][lane] = own + acc;
        }
        __syncthreads();
        if (i < N) {
            float a1 = ba;
#pragma unroll
            for (int k = 0; k < 14; k++) a1 += zs[ln][k] * Wa[k * 64 + lane];
            ts[ln][lane] = fmaxf(a1, 0.0f);
        }
        __syncthreads();
        if (i < N) {
            float a2 = bb;
#pragma unroll
            for (int k = 0; k < 64; k++) a2 += ts[ln][k] * Wb[k * 64 + lane];
            h1[i * 64 + lane] = fmaxf(a2, 0.0f);   // outer relu, layer 1
        }
        __syncthreads();
    }
}

// Layer 2 fused: gather h1[neighbors] + self, MLP, pool-atomics.
__global__ __launch_bounds__(256) void gin_fused2(
    const float* __restrict__ h1,
    const int* __restrict__ offs, const int* __restrict__ deg,
    const int* __restrict__ ssrc,
    const float* __restrict__ W2a, const float* __restrict__ b2a,
    const float* __restrict__ W2b, const float* __restrict__ b2b,
    const int* __restrict__ batch,
    float* __restrict__ sums, float* __restrict__ counts, int N)
{
    __shared__ float Wa[64 * 64];
    __shared__ float Wb[64 * 64];
    __shared__ float zs[4][64];
    __shared__ float ts[4][64];
    for (int i = threadIdx.x; i < 64 * 64; i += 256) {
        Wa[i] = W2a[i];
        Wb[i] = W2b[i];
    }
    __syncthreads();

    int lane = threadIdx.x & 63;
    int ln   = threadIdx.x >> 6;
    float ba = b2a[lane], bb = b2b[lane];

    for (int base = blockIdx.x * 4; base < N; base += gridDim.x * 4) {
        int i = base + ln;
        if (i < N) {
            int st = offs[i], len = deg[i];
            float acc = h1[(size_t)i * 64 + lane];       // self
            for (int k = 0; k < len; k++) {
                int s = ssrc[st + k];
                acc += h1[(size_t)s * 64 + lane];        // coalesced 256B row
            }
            zs[ln][lane] = acc;
        }
        __syncthreads();
        if (i < N) {
            float a1 = ba;
#pragma unroll
            for (int k = 0; k < 64; k++) a1 += zs[ln][k] * Wa[k * 64 + lane];
            ts[ln][lane] = fmaxf(a1, 0.0f);
        }
        __syncthreads();
        if (i < N) {
            float a2 = bb;
#pragma unroll
            for (int k = 0; k < 64; k++) a2 += ts[ln][k] * Wb[k * 64 + lane];
            float h2 = fmaxf(a2, 0.0f);                  // outer relu, layer 2
            int g = batch[i];
            atomicAdd(&sums[g * 64 + lane], h2);
            if (lane == 0) atomicAdd(&counts[g], 1.0f);
        }
        __syncthreads();
    }
}

__global__ __launch_bounds__(256) void gin_final(
    const float* __restrict__ sums, const float* __restrict__ counts,
    const float* __restrict__ Wlin, const float* __restrict__ blin,
    float* __restrict__ out, int G)
{
    int lane = threadIdx.x & 63;
    int g    = blockIdx.x * 4 + (threadIdx.x >> 6);
    if (g < G) {
        float v = sums[g * 64 + lane] * Wlin[lane];
#pragma unroll
        for (int off = 32; off > 0; off >>= 1) v += __shfl_down(v, off, 64);
        if (lane == 0) out[g] = v / fmaxf(counts[g], 1.0f) + blin[0];
    }
}

extern "C" void kernel_launch(void* const* d_in, const int* in_sizes, int n_in,
                              void* d_out, int out_size, void* d_ws, size_t ws_size,
                              hipStream_t stream) {
    const float* x    = (const float*)d_in[0];
    const float* pos  = (const float*)d_in[1];
    const int*   ei   = (const int*)d_in[2];
    const int*   batch= (const int*)d_in[3];
    const float* W1a  = (const float*)d_in[4];
    const float* b1a  = (const float*)d_in[5];
    const float* W1b  = (const float*)d_in[6];
    const float* b1b  = (const float*)d_in[7];
    const float* W2a  = (const float*)d_in[8];
    const float* b2a  = (const float*)d_in[9];
    const float* W2b  = (const float*)d_in[10];
    const float* b2b  = (const float*)d_in[11];
    const float* Wlin = (const float*)d_in[12];
    const float* blin = (const float*)d_in[13];
    float* out = (float*)d_out;

    const int N = in_sizes[0] / 11;     // 50000
    const int E = in_sizes[2] / 2;      // 800000
    const int G = out_size;             // 2500

    const int* src = ei;
    const int* dst = ei + E;

    const int NB = (N + 255) / 256;     // scan blocks (196)

    // Workspace layout (all 4-byte elems):
    // [deg | sums | counts] (memset 0) | offs | cursor | bsum | ssrc | h1
    char* ws = (char*)d_ws;
    size_t o = 0;
    int*   deg    = (int*)(ws + o);   o += (size_t)N * 4;
    float* sums   = (float*)(ws + o); o += (size_t)G * 64 * 4;
    float* counts = (float*)(ws + o); o += (((size_t)G + 63) & ~(size_t)63) * 4;
    size_t zero_bytes = o;
    int*   offs   = (int*)(ws + o);   o += (size_t)N * 4;
    int*   cursor = (int*)(ws + o);   o += (size_t)N * 4;
    int*   bsum   = (int*)(ws + o);   o += 256 * 4;
    int*   ssrc   = (int*)(ws + o);   o += (size_t)E * 4;
    float* h1     = (float*)(ws + o); o += (size_t)N * 64 * 4;

    hipMemsetAsync(ws, 0, zero_bytes, stream);

    // --- CSR build (grouped by dst) ---
    count_deg<<<(E + 255) / 256, 256, 0, stream>>>(dst, deg, E);
    scan1<<<NB, 256, 0, stream>>>(deg, offs, bsum, N);
    scan2<<<1, 256, 0, stream>>>(bsum, NB);
    scan3<<<NB, 256, 0, stream>>>(offs, bsum, cursor, N);
    fill_csr<<<(E + 255) / 256, 256, 0, stream>>>(src, dst, cursor, ssrc, E);

    // --- Fused conv layers ---
    gin_fused1<<<2048, 256, 0, stream>>>(
        x, pos, offs, deg, ssrc, W1a, b1a, W1b, b1b, h1, N);
    gin_fused2<<<2048, 256, 0, stream>>>(
        h1, offs, deg, ssrc, W2a, b2a, W2b, b2b, batch, sums, counts, N);

    gin_final<<<(G + 3) / 4, 256, 0, stream>>>(
        sums, counts, Wlin, blin, out, G);
}

// Round 3
// 383.707 us; speedup vs baseline: 1.0756x; 1.0722x over previous
//
#include <hip/hip_runtime.h>
#include <hip/hip_bf16.h>

// GIN: 2x GINConv(eps=0, MLP 2-layer H=64) + global mean pool + linear.
// N=50000, E=800000, G=2500.
//
// R2: fused gather kernels rebuilt for latency:
//  - neighbor indices: 1 coalesced load + __shfl broadcast (no dependent
//    index-load chain), 4 independent accumulators -> 4 row-loads in flight
//  - MLP: 4 nodes per wave per pass; one LDS weight read feeds 4 FMAs;
//    activations broadcast via v_readlane (no LDS pipe, no barriers)
//  - waves own contiguous 16-node ranges; pooling accumulates in registers,
//    flushes per graph-boundary (sorted batch) instead of per node

#define NPW 16  // nodes per wave

__device__ __forceinline__ float rlane(float v, int k) {
    return __uint_as_float(__builtin_amdgcn_readlane(__float_as_uint(v), k));
}

// ---------------- CSR build (grouped by dst) ----------------

__global__ __launch_bounds__(256) void count_deg(
    const int* __restrict__ dst, int* __restrict__ deg, int E)
{
    int e = blockIdx.x * 256 + threadIdx.x;
    if (e < E) atomicAdd(&deg[dst[e]], 1);
}

__global__ __launch_bounds__(256) void scan1(
    const int* __restrict__ deg, int* __restrict__ offs,
    int* __restrict__ bsum, int N)
{
    __shared__ int wsum[4];
    int i = blockIdx.x * 256 + threadIdx.x;
    int v = (i < N) ? deg[i] : 0;
    int lane = threadIdx.x & 63, w = threadIdx.x >> 6;
    int s = v;
#pragma unroll
    for (int off = 1; off < 64; off <<= 1) {
        int t = __shfl_up(s, off, 64);
        if (lane >= off) s += t;
    }
    if (lane == 63) wsum[w] = s;
    __syncthreads();
    int add = 0;
    for (int j = 0; j < w; j++) add += wsum[j];
    int incl = s + add;
    if (i < N) offs[i] = incl - v;
    if (threadIdx.x == 255) bsum[blockIdx.x] = incl;
}

__global__ __launch_bounds__(256) void scan2(int* __restrict__ bsum, int NB)
{
    __shared__ int wsum[4];
    int i = threadIdx.x;
    int v = (i < NB) ? bsum[i] : 0;
    int lane = threadIdx.x & 63, w = threadIdx.x >> 6;
    int s = v;
#pragma unroll
    for (int off = 1; off < 64; off <<= 1) {
        int t = __shfl_up(s, off, 64);
        if (lane >= off) s += t;
    }
    if (lane == 63) wsum[w] = s;
    __syncthreads();
    int add = 0;
    for (int j = 0; j < w; j++) add += wsum[j];
    int incl = s + add;
    if (i < NB) bsum[i] = incl - v;
}

__global__ __launch_bounds__(256) void scan3(
    int* __restrict__ offs, const int* __restrict__ bsum,
    int* __restrict__ cursor, int N)
{
    int i = blockIdx.x * 256 + threadIdx.x;
    if (i < N) {
        int o = offs[i] + bsum[blockIdx.x];
        offs[i] = o;
        cursor[i] = o;
    }
}

__global__ __launch_bounds__(256) void fill_csr(
    const int* __restrict__ src, const int* __restrict__ dst,
    int* __restrict__ cursor, int* __restrict__ ssrc, int E)
{
    int e = blockIdx.x * 256 + threadIdx.x;
    if (e < E) {
        int p = atomicAdd(&cursor[dst[e]], 1);
        ssrc[p] = src[e];
    }
}

// ---------------- Layer 1 fused ----------------

__global__ __launch_bounds__(256) void gin_fused1(
    const float* __restrict__ x, const float* __restrict__ pos,
    const int* __restrict__ offs, const int* __restrict__ deg,
    const int* __restrict__ ssrc,
    const float* __restrict__ W1a, const float* __restrict__ b1a,
    const float* __restrict__ W1b, const float* __restrict__ b1b,
    float* __restrict__ h1, int N)
{
    __shared__ float Wa[14 * 64];
    __shared__ float Wb[64 * 64];
    for (int i = threadIdx.x; i < 14 * 64; i += 256) Wa[i] = W1a[i];
    for (int i = threadIdx.x; i < 64 * 64; i += 256) Wb[i] = W1b[i];
    __syncthreads();

    int lane = threadIdx.x & 63;
    int wv   = blockIdx.x * 4 + (threadIdx.x >> 6);
    int f    = lane & 15, sub = lane >> 4;
    int base = wv * NPW;
    if (base >= N) return;
    int end = min(base + NPW, N);
    float ba = b1a[lane], bb = b1b[lane];

    for (int g0 = base; g0 < end; g0 += 4) {
        float z[4];
        int   iv[4];
        bool  val[4];
#pragma unroll
        for (int n = 0; n < 4; n++) {
            int i = g0 + n;
            val[n] = (i < end);
            iv[n]  = val[n] ? i : (end - 1);
        }
#pragma unroll
        for (int n = 0; n < 4; n++) {
            int i = iv[n];
            int st = offs[i], len = deg[i];
            float a0 = 0.f, a1 = 0.f;
            int k = 0;
            while (k < len) {
                int chunk = min(len - k, 64);
                int sv = (lane < chunk) ? ssrc[st + k + lane] : 0;
                int m = 0;
                for (; m + 8 <= chunk; m += 8) {
                    int sA = __shfl(sv, m + sub, 64);
                    int sB = __shfl(sv, m + 4 + sub, 64);
                    if (f < 14) {
                        a0 += (f < 11) ? x[sA * 11 + f] : pos[sA * 3 + (f - 11)];
                        a1 += (f < 11) ? x[sB * 11 + f] : pos[sB * 3 + (f - 11)];
                    }
                }
                for (; m < chunk; m += 4) {
                    int jj = m + sub;
                    int s = __shfl(sv, (jj < chunk) ? jj : 0, 64);
                    if (jj < chunk && f < 14)
                        a0 += (f < 11) ? x[s * 11 + f] : pos[s * 3 + (f - 11)];
                }
                k += chunk;
            }
            float a = a0 + a1;
            a += __shfl_xor(a, 16, 64);
            a += __shfl_xor(a, 32, 64);
            if (f < 14)
                a += (f < 11) ? x[i * 11 + f] : pos[i * 3 + (f - 11)];
            z[n] = a;   // lanes 0..13 hold features 0..13
        }
        float t[4], o[4];
#pragma unroll
        for (int n = 0; n < 4; n++) t[n] = ba;
#pragma unroll
        for (int k = 0; k < 14; k++) {
            float wa = Wa[k * 64 + lane];
#pragma unroll
            for (int n = 0; n < 4; n++) t[n] += rlane(z[n], k) * wa;
        }
#pragma unroll
        for (int n = 0; n < 4; n++) { t[n] = fmaxf(t[n], 0.f); o[n] = bb; }
#pragma unroll
        for (int k = 0; k < 64; k++) {
            float wb = Wb[k * 64 + lane];
#pragma unroll
            for (int n = 0; n < 4; n++) o[n] += rlane(t[n], k) * wb;
        }
#pragma unroll
        for (int n = 0; n < 4; n++)
            if (val[n]) h1[(size_t)iv[n] * 64 + lane] = fmaxf(o[n], 0.f);
    }
}

// ---------------- Layer 2 fused + pooling ----------------

__global__ __launch_bounds__(256) void gin_fused2(
    const float* __restrict__ h1,
    const int* __restrict__ offs, const int* __restrict__ deg,
    const int* __restrict__ ssrc,
    const float* __restrict__ W2a, const float* __restrict__ b2a,
    const float* __restrict__ W2b, const float* __restrict__ b2b,
    const int* __restrict__ batch,
    float* __restrict__ sums, float* __restrict__ counts, int N)
{
    __shared__ float Wa[64 * 64];
    __shared__ float Wb[64 * 64];
    for (int i = threadIdx.x; i < 64 * 64; i += 256) {
        Wa[i] = W2a[i];
        Wb[i] = W2b[i];
    }
    __syncthreads();

    int lane = threadIdx.x & 63;
    int wv   = blockIdx.x * 4 + (threadIdx.x >> 6);
    int base = wv * NPW;
    if (base >= N) return;
    int end = min(base + NPW, N);
    float ba = b2a[lane], bb = b2b[lane];

    int gcur = -1; float ps = 0.f; int cnt = 0;

    for (int g0 = base; g0 < end; g0 += 4) {
        float z[4];
        int   iv[4];
        bool  val[4];
#pragma unroll
        for (int n = 0; n < 4; n++) {
            int i = g0 + n;
            val[n] = (i < end);
            iv[n]  = val[n] ? i : (end - 1);
        }
#pragma unroll
        for (int n = 0; n < 4; n++) {
            int i = iv[n];
            int st = offs[i], len = deg[i];
            float a0 = h1[(size_t)i * 64 + lane];  // self
            float a1 = 0.f, a2 = 0.f, a3 = 0.f;
            int k = 0;
            while (k < len) {
                int chunk = min(len - k, 64);
                int sv = (lane < chunk) ? ssrc[st + k + lane] : 0;
                int j = 0;
                for (; j + 4 <= chunk; j += 4) {
                    int s0 = __shfl(sv, j,     64);
                    int s1 = __shfl(sv, j + 1, 64);
                    int s2 = __shfl(sv, j + 2, 64);
                    int s3 = __shfl(sv, j + 3, 64);
                    a0 += h1[(size_t)s0 * 64 + lane];
                    a1 += h1[(size_t)s1 * 64 + lane];
                    a2 += h1[(size_t)s2 * 64 + lane];
                    a3 += h1[(size_t)s3 * 64 + lane];
                }
                for (; j < chunk; j++) {
                    int s = __shfl(sv, j, 64);
                    a0 += h1[(size_t)s * 64 + lane];
                }
                k += chunk;
            }
            z[n] = (a0 + a1) + (a2 + a3);
        }
        float t[4], o[4];
#pragma unroll
        for (int n = 0; n < 4; n++) t[n] = ba;
#pragma unroll
        for (int k = 0; k < 64; k++) {
            float wa = Wa[k * 64 + lane];
#pragma unroll
            for (int n = 0; n < 4; n++) t[n] += rlane(z[n], k) * wa;
        }
#pragma unroll
        for (int n = 0; n < 4; n++) { t[n] = fmaxf(t[n], 0.f); o[n] = bb; }
#pragma unroll
        for (int k = 0; k < 64; k++) {
            float wb = Wb[k * 64 + lane];
#pragma unroll
            for (int n = 0; n < 4; n++) o[n] += rlane(t[n], k) * wb;
        }
#pragma unroll
        for (int n = 0; n < 4; n++) {
            if (!val[n]) continue;
            float h2 = fmaxf(o[n], 0.f);
            int gi = batch[iv[n]];
            if (gi != gcur) {
                if (gcur >= 0) {
                    atomicAdd(&sums[gcur * 64 + lane], ps);
                    if (lane == 0) atomicAdd(&counts[gcur], (float)cnt);
                }
                gcur = gi; ps = 0.f; cnt = 0;
            }
            ps += h2; cnt++;
        }
    }
    if (gcur >= 0) {
        atomicAdd(&sums[gcur * 64 + lane], ps);
        if (lane == 0) atomicAdd(&counts[gcur], (float)cnt);
    }
}

__global__ __launch_bounds__(256) void gin_final(
    const float* __restrict__ sums, const float* __restrict__ counts,
    const float* __restrict__ Wlin, const float* __restrict__ blin,
    float* __restrict__ out, int G)
{
    int lane = threadIdx.x & 63;
    int g    = blockIdx.x * 4 + (threadIdx.x >> 6);
    if (g < G) {
        float v = sums[g * 64 + lane] * Wlin[lane];
#pragma unroll
        for (int off = 32; off > 0; off >>= 1) v += __shfl_down(v, off, 64);
        if (lane == 0) out[g] = v / fmaxf(counts[g], 1.0f) + blin[0];
    }
}

extern "C" void kernel_launch(void* const* d_in, const int* in_sizes, int n_in,
                              void* d_out, int out_size, void* d_ws, size_t ws_size,
                              hipStream_t stream) {
    const float* x    = (const float*)d_in[0];
    const float* pos  = (const float*)d_in[1];
    const int*   ei   = (const int*)d_in[2];
    const int*   batch= (const int*)d_in[3];
    const float* W1a  = (const float*)d_in[4];
    const float* b1a  = (const float*)d_in[5];
    const float* W1b  = (const float*)d_in[6];
    const float* b1b  = (const float*)d_in[7];
    const float* W2a  = (const float*)d_in[8];
    const float* b2a  = (const float*)d_in[9];
    const float* W2b  = (const float*)d_in[10];
    const float* b2b  = (const float*)d_in[11];
    const float* Wlin = (const float*)d_in[12];
    const float* blin = (const float*)d_in[13];
    float* out = (float*)d_out;

    const int N = in_sizes[0] / 11;     // 50000
    const int E = in_sizes[2] / 2;      // 800000
    const int G = out_size;             // 2500

    const int* src = ei;
    const int* dst = ei + E;

    const int NB = (N + 255) / 256;

    // Workspace: [deg | sums | counts] (memset 0) | offs | cursor | bsum | ssrc | h1
    char* ws = (char*)d_ws;
    size_t o = 0;
    int*   deg    = (int*)(ws + o);   o += (size_t)N * 4;
    float* sums   = (float*)(ws + o); o += (size_t)G * 64 * 4;
    float* counts = (float*)(ws + o); o += (((size_t)G + 63) & ~(size_t)63) * 4;
    size_t zero_bytes = o;
    int*   offs   = (int*)(ws + o);   o += (size_t)N * 4;
    int*   cursor = (int*)(ws + o);   o += (size_t)N * 4;
    int*   bsum   = (int*)(ws + o);   o += 256 * 4;
    int*   ssrc   = (int*)(ws + o);   o += (size_t)E * 4;
    float* h1     = (float*)(ws + o); o += (size_t)N * 64 * 4;

    hipMemsetAsync(ws, 0, zero_bytes, stream);

    count_deg<<<(E + 255) / 256, 256, 0, stream>>>(dst, deg, E);
    scan1<<<NB, 256, 0, stream>>>(deg, offs, bsum, N);
    scan2<<<1, 256, 0, stream>>>(bsum, NB);
    scan3<<<NB, 256, 0, stream>>>(offs, bsum, cursor, N);
    fill_csr<<<(E + 255) / 256, 256, 0, stream>>>(src, dst, cursor, ssrc, E);

    const int nwaves = (N + NPW - 1) / NPW;          // 3125
    const int nblk   = (nwaves + 3) / 4;             // 782

    gin_fused1<<<nblk, 256, 0, stream>>>(
        x, pos, offs, deg, ssrc, W1a, b1a, W1b, b1b, h1, N);
    gin_fused2<<<nblk, 256, 0, stream>>>(
        h1, offs, deg, ssrc, W2a, b2a, W2b, b2b, batch, sums, counts, N);

    gin_final<<<(G + 3) / 4, 256, 0, stream>>>(
        sums, counts, Wlin, blin, out, G);
}

// Round 4
// 342.647 us; speedup vs baseline: 1.2045x; 1.1198x over previous
//
#include <hip/hip_runtime.h>
#include <hip/hip_bf16.h>

// GIN: 2x GINConv(eps=0, MLP 2-layer H=64) + global mean pool + linear.
// N=50000, E=800000, G=2500.
//
// R3: h1 stored as PACKED BF16 (row = 128 B = 32 dwords; dword p holds
// features 2p,2p+1). Layer-2 gather fetches TWO neighbor rows per load
// instruction (half-wave per row), 4 chains -> 8 rows in flight, and total
// gather bytes halve (h1 6.4 MB nearly L2-resident). NPW=8 doubles waves.

#define NPW 8  // nodes per wave

typedef unsigned int uint;

__device__ __forceinline__ float rlane(float v, int k) {
    return __uint_as_float(__builtin_amdgcn_readlane(__float_as_uint(v), k));
}
__device__ __forceinline__ float bflo(uint d) { return __uint_as_float(d << 16); }
__device__ __forceinline__ float bfhi(uint d) { return __uint_as_float(d & 0xffff0000u); }
__device__ __forceinline__ uint bfpack(float lo, float hi) {
    uint ul = __float_as_uint(lo), uh = __float_as_uint(hi);
    ul += 0x7fffu + ((ul >> 16) & 1u);          // RNE
    uh += 0x7fffu + ((uh >> 16) & 1u);
    return (ul >> 16) | (uh & 0xffff0000u);
}

// ---------------- CSR build (grouped by dst) ----------------

__global__ __launch_bounds__(256) void count_deg(
    const int* __restrict__ dst, int* __restrict__ deg, int E)
{
    int e = blockIdx.x * 256 + threadIdx.x;
    if (e < E) atomicAdd(&deg[dst[e]], 1);
}

__global__ __launch_bounds__(256) void scan1(
    const int* __restrict__ deg, int* __restrict__ offs,
    int* __restrict__ bsum, int N)
{
    __shared__ int wsum[4];
    int i = blockIdx.x * 256 + threadIdx.x;
    int v = (i < N) ? deg[i] : 0;
    int lane = threadIdx.x & 63, w = threadIdx.x >> 6;
    int s = v;
#pragma unroll
    for (int off = 1; off < 64; off <<= 1) {
        int t = __shfl_up(s, off, 64);
        if (lane >= off) s += t;
    }
    if (lane == 63) wsum[w] = s;
    __syncthreads();
    int add = 0;
    for (int j = 0; j < w; j++) add += wsum[j];
    int incl = s + add;
    if (i < N) offs[i] = incl - v;
    if (threadIdx.x == 255) bsum[blockIdx.x] = incl;
}

__global__ __launch_bounds__(256) void scan2(int* __restrict__ bsum, int NB)
{
    __shared__ int wsum[4];
    int i = threadIdx.x;
    int v = (i < NB) ? bsum[i] : 0;
    int lane = threadIdx.x & 63, w = threadIdx.x >> 6;
    int s = v;
#pragma unroll
    for (int off = 1; off < 64; off <<= 1) {
        int t = __shfl_up(s, off, 64);
        if (lane >= off) s += t;
    }
    if (lane == 63) wsum[w] = s;
    __syncthreads();
    int add = 0;
    for (int j = 0; j < w; j++) add += wsum[j];
    int incl = s + add;
    if (i < NB) bsum[i] = incl - v;
}

__global__ __launch_bounds__(256) void scan3(
    int* __restrict__ offs, const int* __restrict__ bsum,
    int* __restrict__ cursor, int N)
{
    int i = blockIdx.x * 256 + threadIdx.x;
    if (i < N) {
        int o = offs[i] + bsum[blockIdx.x];
        offs[i] = o;
        cursor[i] = o;
    }
}

__global__ __launch_bounds__(256) void fill_csr(
    const int* __restrict__ src, const int* __restrict__ dst,
    int* __restrict__ cursor, int* __restrict__ ssrc, int E)
{
    int e = blockIdx.x * 256 + threadIdx.x;
    if (e < E) {
        int p = atomicAdd(&cursor[dst[e]], 1);
        ssrc[p] = src[e];
    }
}

// ---------------- Layer 1 fused (f32 gather -> MLP -> bf16 h1) ----------------

__global__ __launch_bounds__(256) void gin_fused1(
    const float* __restrict__ x, const float* __restrict__ pos,
    const int* __restrict__ offs, const int* __restrict__ deg,
    const int* __restrict__ ssrc,
    const float* __restrict__ W1a, const float* __restrict__ b1a,
    const float* __restrict__ W1b, const float* __restrict__ b1b,
    uint* __restrict__ h1p, int N)
{
    __shared__ float Wa[14 * 64];
    __shared__ float Wb[64 * 64];
    for (int i = threadIdx.x; i < 14 * 64; i += 256) Wa[i] = W1a[i];
    for (int i = threadIdx.x; i < 64 * 64; i += 256) Wb[i] = W1b[i];
    __syncthreads();

    int lane = threadIdx.x & 63;
    int p    = lane & 31, half = lane >> 5;
    int wv   = blockIdx.x * 4 + (threadIdx.x >> 6);
    int f    = lane & 15, sub = lane >> 4;
    int base = wv * NPW;
    if (base >= N) return;
    int end = min(base + NPW, N);
    float ba = b1a[lane], bb = b1b[lane];

    for (int g0 = base; g0 < end; g0 += 4) {
        float z[4];
        int   iv[4];
#pragma unroll
        for (int n = 0; n < 4; n++) iv[n] = min(g0 + n, end - 1);
#pragma unroll
        for (int n = 0; n < 4; n++) {
            int i = iv[n];
            int st = offs[i], len = deg[i];
            float a0 = 0.f, a1 = 0.f;
            int k = 0;
            while (k < len) {
                int chunk = min(len - k, 64);
                int sv = ssrc[st + k + min(lane, chunk - 1)];
                int m = 0;
                for (; m + 8 <= chunk; m += 8) {
                    int sA = __shfl(sv, m + sub, 64);
                    int sB = __shfl(sv, m + 4 + sub, 64);
                    if (f < 14) {
                        a0 += (f < 11) ? x[sA * 11 + f] : pos[sA * 3 + (f - 11)];
                        a1 += (f < 11) ? x[sB * 11 + f] : pos[sB * 3 + (f - 11)];
                    }
                }
                for (; m < chunk; m += 4) {
                    int jj = m + sub;
                    int s = __shfl(sv, (jj < chunk) ? jj : 0, 64);
                    if (jj < chunk && f < 14)
                        a0 += (f < 11) ? x[s * 11 + f] : pos[s * 3 + (f - 11)];
                }
                k += chunk;
            }
            float a = a0 + a1;
            a += __shfl_xor(a, 16, 64);
            a += __shfl_xor(a, 32, 64);
            if (f < 14)
                a += (f < 11) ? x[i * 11 + f] : pos[i * 3 + (f - 11)];
            z[n] = a;   // lanes 0..13 hold features 0..13
        }
        float t[4], o[4];
#pragma unroll
        for (int n = 0; n < 4; n++) t[n] = ba;
#pragma unroll
        for (int k = 0; k < 14; k++) {
            float wa = Wa[k * 64 + lane];
#pragma unroll
            for (int n = 0; n < 4; n++) t[n] += rlane(z[n], k) * wa;
        }
#pragma unroll
        for (int n = 0; n < 4; n++) { t[n] = fmaxf(t[n], 0.f); o[n] = bb; }
#pragma unroll
        for (int k = 0; k < 64; k++) {
            float wb = Wb[k * 64 + lane];
#pragma unroll
            for (int n = 0; n < 4; n++) o[n] += rlane(t[n], k) * wb;
        }
#pragma unroll
        for (int n = 0; n < 4; n++) o[n] = fmaxf(o[n], 0.f);  // outer relu L1
        // pack pairs of rows -> one full-wave 256B store per 2 nodes
#pragma unroll
        for (int n = 0; n < 4; n += 2) {
            float al = __shfl(o[n],     2 * p,     64);
            float ah = __shfl(o[n],     2 * p + 1, 64);
            float bl = __shfl(o[n + 1], 2 * p,     64);
            float bh = __shfl(o[n + 1], 2 * p + 1, 64);
            uint dw = half ? bfpack(bl, bh) : bfpack(al, ah);
            int node = g0 + n + half;
            if (node < end) h1p[(size_t)node * 32 + p] = dw;
        }
    }
}

// ---------------- Layer 2 fused (bf16 2-row gather) + pooling ----------------

__global__ __launch_bounds__(256) void gin_fused2(
    const uint* __restrict__ h1p,
    const int* __restrict__ offs, const int* __restrict__ deg,
    const int* __restrict__ ssrc,
    const float* __restrict__ W2a, const float* __restrict__ b2a,
    const float* __restrict__ W2b, const float* __restrict__ b2b,
    const int* __restrict__ batch,
    float* __restrict__ sums, float* __restrict__ counts, int N)
{
    __shared__ float Wa[64 * 64];
    __shared__ float Wb[64 * 64];
    for (int i = threadIdx.x; i < 64 * 64; i += 256) {
        Wa[i] = W2a[i];
        Wb[i] = W2b[i];
    }
    __syncthreads();

    int lane = threadIdx.x & 63;
    int p    = lane & 31, half = lane >> 5;
    int wv   = blockIdx.x * 4 + (threadIdx.x >> 6);
    int base = wv * NPW;
    if (base >= N) return;
    int end = min(base + NPW, N);
    float ba = b2a[lane], bb = b2b[lane];

    int gcur = -1; float ps = 0.f; int cnt = 0;

    for (int g0 = base; g0 < end; g0 += 4) {
        float zlo[4], zhi[4];
        int   iv[4];
        bool  val[4];
#pragma unroll
        for (int n = 0; n < 4; n++) {
            val[n] = (g0 + n < end);
            iv[n]  = min(g0 + n, end - 1);
        }
#pragma unroll
        for (int n = 0; n < 4; n++) {
            int i = iv[n];
            int st = offs[i], len = deg[i];
            float c0l = 0.f, c0h = 0.f, c1l = 0.f, c1h = 0.f;
            float c2l = 0.f, c2h = 0.f, c3l = 0.f, c3h = 0.f;
            int k = 0;
            while (k < len) {
                int chunk = min(len - k, 64);
                int sv = ssrc[st + k + min(lane, chunk - 1)];
                int t = 0;
                for (; t + 8 <= chunk; t += 8) {   // 8 rows / 4 loads
                    int s0 = __shfl(sv, t     + half, 64);
                    int s1 = __shfl(sv, t + 2 + half, 64);
                    int s2 = __shfl(sv, t + 4 + half, 64);
                    int s3 = __shfl(sv, t + 6 + half, 64);
                    uint d0 = h1p[(size_t)s0 * 32 + p];
                    uint d1 = h1p[(size_t)s1 * 32 + p];
                    uint d2 = h1p[(size_t)s2 * 32 + p];
                    uint d3 = h1p[(size_t)s3 * 32 + p];
                    c0l += bflo(d0); c0h += bfhi(d0);
                    c1l += bflo(d1); c1h += bfhi(d1);
                    c2l += bflo(d2); c2h += bfhi(d2);
                    c3l += bflo(d3); c3h += bfhi(d3);
                }
                for (; t + 2 <= chunk; t += 2) {   // 2 rows / load
                    int s0 = __shfl(sv, t + half, 64);
                    uint d0 = h1p[(size_t)s0 * 32 + p];
                    c0l += bflo(d0); c0h += bfhi(d0);
                }
                if (t < chunk) {                   // odd remainder: 1 row
                    int s0 = __shfl(sv, t, 64);
                    uint d0 = h1p[(size_t)s0 * 32 + p];
                    if (half == 0) { c0l += bflo(d0); c0h += bfhi(d0); }
                }
                k += chunk;
            }
            float zl = (c0l + c1l) + (c2l + c3l);
            float zh = (c0h + c1h) + (c2h + c3h);
            zl += __shfl_xor(zl, 32, 64);
            zh += __shfl_xor(zh, 32, 64);
            uint ds = h1p[(size_t)i * 32 + p];     // self (both halves same)
            zlo[n] = zl + bflo(ds);
            zhi[n] = zh + bfhi(ds);
        }
        float t4[4], o[4];
#pragma unroll
        for (int n = 0; n < 4; n++) t4[n] = ba;
#pragma unroll
        for (int k = 0; k < 64; k += 2) {
            float wa0 = Wa[k * 64 + lane];
            float wa1 = Wa[(k + 1) * 64 + lane];
            int q = k >> 1;
#pragma unroll
            for (int n = 0; n < 4; n++)
                t4[n] += rlane(zlo[n], q) * wa0 + rlane(zhi[n], q) * wa1;
        }
#pragma unroll
        for (int n = 0; n < 4; n++) { t4[n] = fmaxf(t4[n], 0.f); o[n] = bb; }
#pragma unroll
        for (int k = 0; k < 64; k++) {
            float wb = Wb[k * 64 + lane];
#pragma unroll
            for (int n = 0; n < 4; n++) o[n] += rlane(t4[n], k) * wb;
        }
#pragma unroll
        for (int n = 0; n < 4; n++) {
            if (!val[n]) continue;
            float h2 = fmaxf(o[n], 0.f);           // outer relu L2
            int gi = batch[iv[n]];
            if (gi != gcur) {
                if (gcur >= 0) {
                    atomicAdd(&sums[gcur * 64 + lane], ps);
                    if (lane == 0) atomicAdd(&counts[gcur], (float)cnt);
                }
                gcur = gi; ps = 0.f; cnt = 0;
            }
            ps += h2; cnt++;
        }
    }
    if (gcur >= 0) {
        atomicAdd(&sums[gcur * 64 + lane], ps);
        if (lane == 0) atomicAdd(&counts[gcur], (float)cnt);
    }
}

__global__ __launch_bounds__(256) void gin_final(
    const float* __restrict__ sums, const float* __restrict__ counts,
    const float* __restrict__ Wlin, const float* __restrict__ blin,
    float* __restrict__ out, int G)
{
    int lane = threadIdx.x & 63;
    int g    = blockIdx.x * 4 + (threadIdx.x >> 6);
    if (g < G) {
        float v = sums[g * 64 + lane] * Wlin[lane];
#pragma unroll
        for (int off = 32; off > 0; off >>= 1) v += __shfl_down(v, off, 64);
        if (lane == 0) out[g] = v / fmaxf(counts[g], 1.0f) + blin[0];
    }
}

extern "C" void kernel_launch(void* const* d_in, const int* in_sizes, int n_in,
                              void* d_out, int out_size, void* d_ws, size_t ws_size,
                              hipStream_t stream) {
    const float* x    = (const float*)d_in[0];
    const float* pos  = (const float*)d_in[1];
    const int*   ei   = (const int*)d_in[2];
    const int*   batch= (const int*)d_in[3];
    const float* W1a  = (const float*)d_in[4];
    const float* b1a  = (const float*)d_in[5];
    const float* W1b  = (const float*)d_in[6];
    const float* b1b  = (const float*)d_in[7];
    const float* W2a  = (const float*)d_in[8];
    const float* b2a  = (const float*)d_in[9];
    const float* W2b  = (const float*)d_in[10];
    const float* b2b  = (const float*)d_in[11];
    const float* Wlin = (const float*)d_in[12];
    const float* blin = (const float*)d_in[13];
    float* out = (float*)d_out;

    const int N = in_sizes[0] / 11;     // 50000
    const int E = in_sizes[2] / 2;      // 800000
    const int G = out_size;             // 2500

    const int* src = ei;
    const int* dst = ei + E;

    const int NB = (N + 255) / 256;

    // Workspace: [deg | sums | counts] (memset 0) | offs | cursor | bsum | ssrc | h1(bf16 packed)
    char* ws = (char*)d_ws;
    size_t o = 0;
    int*   deg    = (int*)(ws + o);   o += (size_t)N * 4;
    float* sums   = (float*)(ws + o); o += (size_t)G * 64 * 4;
    float* counts = (float*)(ws + o); o += (((size_t)G + 63) & ~(size_t)63) * 4;
    size_t zero_bytes = o;
    int*   offs   = (int*)(ws + o);   o += (size_t)N * 4;
    int*   cursor = (int*)(ws + o);   o += (size_t)N * 4;
    int*   bsum   = (int*)(ws + o);   o += 256 * 4;
    int*   ssrc   = (int*)(ws + o);   o += (size_t)E * 4;
    o = (o + 255) & ~(size_t)255;
    uint*  h1p    = (uint*)(ws + o);  o += (size_t)N * 32 * 4;

    hipMemsetAsync(ws, 0, zero_bytes, stream);

    count_deg<<<(E + 255) / 256, 256, 0, stream>>>(dst, deg, E);
    scan1<<<NB, 256, 0, stream>>>(deg, offs, bsum, N);
    scan2<<<1, 256, 0, stream>>>(bsum, NB);
    scan3<<<NB, 256, 0, stream>>>(offs, bsum, cursor, N);
    fill_csr<<<(E + 255) / 256, 256, 0, stream>>>(src, dst, cursor, ssrc, E);

    const int nwaves = (N + NPW - 1) / NPW;          // 6250
    const int nblk   = (nwaves + 3) / 4;             // 1563

    gin_fused1<<<nblk, 256, 0, stream>>>(
        x, pos, offs, deg, ssrc, W1a, b1a, W1b, b1b, h1p, N);
    gin_fused2<<<nblk, 256, 0, stream>>>(
        h1p, offs, deg, ssrc, W2a, b2a, W2b, b2b, batch, sums, counts, N);

    gin_final<<<(G + 3) / 4, 256, 0, stream>>>(
        sums, counts, Wlin, blin, out, G);
}

// Round 5
// 286.209 us; speedup vs baseline: 1.4421x; 1.1972x over previous
//
#include <hip/hip_runtime.h>
#include <hip/hip_fp16.h>

// GIN: 2x GINConv(eps=0, MLP 2-layer H=64) + global mean pool + linear.
// N=50000, E=800000, G=2500.
//
// R4: split gather from MLP. Gather kernels are 1-wave-per-node, low-VGPR,
// 8 waves/SIMD, loads-only -> latency hidden by wave count. MLP kernels are
// dense readlane-GEMVs over sequential z arrays -> near VALU-issue floor.
// h1 and z1 stored packed f16 (L2-resident; z1 aliases z0 to cap ws size).

typedef unsigned int uint;

__device__ __forceinline__ float rlane(float v, int k) {
    return __uint_as_float(__builtin_amdgcn_readlane(__float_as_uint(v), k));
}

// ---------------- CSR build (grouped by dst) ----------------

__global__ __launch_bounds__(256) void count_deg(
    const int* __restrict__ dst, int* __restrict__ deg, int E)
{
    int e = blockIdx.x * 256 + threadIdx.x;
    if (e < E) atomicAdd(&deg[dst[e]], 1);
}

__global__ __launch_bounds__(256) void scan1(
    const int* __restrict__ deg, int* __restrict__ offs,
    int* __restrict__ bsum, int N)
{
    __shared__ int wsum[4];
    int i = blockIdx.x * 256 + threadIdx.x;
    int v = (i < N) ? deg[i] : 0;
    int lane = threadIdx.x & 63, w = threadIdx.x >> 6;
    int s = v;
#pragma unroll
    for (int off = 1; off < 64; off <<= 1) {
        int t = __shfl_up(s, off, 64);
        if (lane >= off) s += t;
    }
    if (lane == 63) wsum[w] = s;
    __syncthreads();
    int add = 0;
    for (int j = 0; j < w; j++) add += wsum[j];
    int incl = s + add;
    if (i < N) offs[i] = incl - v;
    if (threadIdx.x == 255) bsum[blockIdx.x] = incl;
}

__global__ __launch_bounds__(256) void scan2(int* __restrict__ bsum, int NB)
{
    __shared__ int wsum[4];
    int i = threadIdx.x;
    int v = (i < NB) ? bsum[i] : 0;
    int lane = threadIdx.x & 63, w = threadIdx.x >> 6;
    int s = v;
#pragma unroll
    for (int off = 1; off < 64; off <<= 1) {
        int t = __shfl_up(s, off, 64);
        if (lane >= off) s += t;
    }
    if (lane == 63) wsum[w] = s;
    __syncthreads();
    int add = 0;
    for (int j = 0; j < w; j++) add += wsum[j];
    int incl = s + add;
    if (i < NB) bsum[i] = incl - v;
}

__global__ __launch_bounds__(256) void scan3(
    int* __restrict__ offs, const int* __restrict__ bsum,
    int* __restrict__ cursor, int N)
{
    int i = blockIdx.x * 256 + threadIdx.x;
    if (i < N) {
        int o = offs[i] + bsum[blockIdx.x];
        offs[i] = o;
        cursor[i] = o;
    }
}

__global__ __launch_bounds__(256) void fill_csr(
    const int* __restrict__ src, const int* __restrict__ dst,
    int* __restrict__ cursor, int* __restrict__ ssrc, int E)
{
    int e = blockIdx.x * 256 + threadIdx.x;
    if (e < E) {
        int p = atomicAdd(&cursor[dst[e]], 1);
        ssrc[p] = src[e];
    }
}

// ---------------- gather1: z0 = self + sum_nbr concat(x,pos), f32 [N x 16] ----

__global__ __launch_bounds__(256) void gather1(
    const float* __restrict__ x, const float* __restrict__ pos,
    const int* __restrict__ offs, const int* __restrict__ deg,
    const int* __restrict__ ssrc,
    float* __restrict__ z0, int N)
{
    int lane = threadIdx.x & 63;
    int i = blockIdx.x * 4 + (threadIdx.x >> 6);
    if (i >= N) return;
    int f = lane & 15, sub = lane >> 4;
    int st = offs[i], len = deg[i];
    float a0 = 0.f, a1 = 0.f;
    int k = 0;
    while (k < len) {
        int chunk = min(len - k, 64);
        int sv = ssrc[st + k + min(lane, chunk - 1)];
        int m = 0;
        for (; m + 8 <= chunk; m += 8) {
            int sA = __shfl(sv, m + sub, 64);
            int sB = __shfl(sv, m + 4 + sub, 64);
            if (f < 14) {
                a0 += (f < 11) ? x[sA * 11 + f] : pos[sA * 3 + (f - 11)];
                a1 += (f < 11) ? x[sB * 11 + f] : pos[sB * 3 + (f - 11)];
            }
        }
        for (; m < chunk; m += 4) {
            int jj = m + sub;
            int s = __shfl(sv, (jj < chunk) ? jj : 0, 64);
            if (jj < chunk && f < 14)
                a0 += (f < 11) ? x[s * 11 + f] : pos[s * 3 + (f - 11)];
        }
        k += chunk;
    }
    float a = a0 + a1;
    a += __shfl_xor(a, 16, 64);
    a += __shfl_xor(a, 32, 64);
    if (f < 14) a += (f < 11) ? x[i * 11 + f] : pos[i * 3 + (f - 11)];
    if (lane < 16) z0[(size_t)i * 16 + lane] = (lane < 14) ? a : 0.f;
}

// ---------------- mlp1: h1 = relu(MLP(z0)) -> packed f16 [N x 32 dwords] ----

__global__ __launch_bounds__(256) void mlp1(
    const float* __restrict__ z0,
    const float* __restrict__ W1a, const float* __restrict__ b1a,
    const float* __restrict__ W1b, const float* __restrict__ b1b,
    uint* __restrict__ h1p, int N)
{
    __shared__ float Wa[14 * 64];
    __shared__ float Wb[64 * 64];
    for (int i = threadIdx.x; i < 14 * 64; i += 256) Wa[i] = W1a[i];
    for (int i = threadIdx.x; i < 64 * 64; i += 256) Wb[i] = W1b[i];
    __syncthreads();

    int lane = threadIdx.x & 63;
    int wv = blockIdx.x * 4 + (threadIdx.x >> 6);
    int i0 = wv * 4;                       // N divisible by 4: no partials
    if (i0 >= N) return;

    // lane holds feat (lane&15) of node i0+(lane>>4)
    float zl = z0[(size_t)i0 * 16 + lane];
    float ba = b1a[lane], bb = b1b[lane];

    float t[4], o[4];
#pragma unroll
    for (int n = 0; n < 4; n++) t[n] = ba;
#pragma unroll
    for (int k = 0; k < 14; k++) {
        float wa = Wa[k * 64 + lane];
#pragma unroll
        for (int n = 0; n < 4; n++) t[n] += rlane(zl, n * 16 + k) * wa;
    }
#pragma unroll
    for (int n = 0; n < 4; n++) { t[n] = fmaxf(t[n], 0.f); o[n] = bb; }
#pragma unroll
    for (int k = 0; k < 64; k++) {
        float wb = Wb[k * 64 + lane];
#pragma unroll
        for (int n = 0; n < 4; n++) o[n] += rlane(t[n], k) * wb;
    }
#pragma unroll
    for (int n = 0; n < 4; n++) o[n] = fmaxf(o[n], 0.f);  // outer relu L1

    // pack f16 rows: per pair of nodes one full-wave 128B store
    int p = lane & 31, half = lane >> 5;
#pragma unroll
    for (int pr = 0; pr < 2; pr++) {
        float lo0 = __shfl(o[2 * pr],     2 * p,     64);
        float hi0 = __shfl(o[2 * pr],     2 * p + 1, 64);
        float lo1 = __shfl(o[2 * pr + 1], 2 * p,     64);
        float hi1 = __shfl(o[2 * pr + 1], 2 * p + 1, 64);
        float lo = half ? lo1 : lo0;
        float hi = half ? hi1 : hi0;
        __half2 h = __halves2half2(__float2half(lo), __float2half(hi));
        h1p[(size_t)(i0 + 2 * pr + half) * 32 + p] = *(uint*)&h;
    }
}

// ---------------- gather2: z1 = self + sum_nbr h1 -> packed f16 [N x 32] ----

__global__ __launch_bounds__(256) void gather2(
    const uint* __restrict__ h1p,
    const int* __restrict__ offs, const int* __restrict__ deg,
    const int* __restrict__ ssrc,
    uint* __restrict__ z1p, int N)
{
    int lane = threadIdx.x & 63;
    int i = blockIdx.x * 4 + (threadIdx.x >> 6);
    if (i >= N) return;
    int p = lane & 31, half = lane >> 5;
    int st = offs[i], len = deg[i];
    float c0l = 0.f, c0h = 0.f, c1l = 0.f, c1h = 0.f;
    float c2l = 0.f, c2h = 0.f, c3l = 0.f, c3h = 0.f;
    int k = 0;
    while (k < len) {
        int chunk = min(len - k, 64);
        int sv = ssrc[st + k + min(lane, chunk - 1)];
        int t = 0;
        for (; t + 8 <= chunk; t += 8) {       // 8 rows via 4 dual-row loads
            int s0 = __shfl(sv, t     + half, 64);
            int s1 = __shfl(sv, t + 2 + half, 64);
            int s2 = __shfl(sv, t + 4 + half, 64);
            int s3 = __shfl(sv, t + 6 + half, 64);
            uint d0 = h1p[(size_t)s0 * 32 + p];
            uint d1 = h1p[(size_t)s1 * 32 + p];
            uint d2 = h1p[(size_t)s2 * 32 + p];
            uint d3 = h1p[(size_t)s3 * 32 + p];
            __half2 h0 = *(__half2*)&d0, h1_ = *(__half2*)&d1;
            __half2 h2 = *(__half2*)&d2, h3 = *(__half2*)&d3;
            c0l += __low2float(h0); c0h += __high2float(h0);
            c1l += __low2float(h1_); c1h += __high2float(h1_);
            c2l += __low2float(h2); c2h += __high2float(h2);
            c3l += __low2float(h3); c3h += __high2float(h3);
        }
        for (; t + 2 <= chunk; t += 2) {
            int s0 = __shfl(sv, t + half, 64);
            uint d0 = h1p[(size_t)s0 * 32 + p];
            __half2 h0 = *(__half2*)&d0;
            c0l += __low2float(h0); c0h += __high2float(h0);
        }
        if (t < chunk) {
            int s0 = __shfl(sv, t, 64);
            uint d0 = h1p[(size_t)s0 * 32 + p];
            __half2 h0 = *(__half2*)&d0;
            if (half == 0) { c0l += __low2float(h0); c0h += __high2float(h0); }
        }
        k += chunk;
    }
    float zl = (c0l + c1l) + (c2l + c3l);
    float zh = (c0h + c1h) + (c2h + c3h);
    zl += __shfl_xor(zl, 32, 64);
    zh += __shfl_xor(zh, 32, 64);
    uint ds = h1p[(size_t)i * 32 + p];         // self row
    __half2 hs = *(__half2*)&ds;
    zl += __low2float(hs);
    zh += __high2float(hs);
    if (half == 0) {
        __half2 zo = __halves2half2(__float2half(zl), __float2half(zh));
        z1p[(size_t)i * 32 + p] = *(uint*)&zo;
    }
}

// ---------------- mlp2 + pooling ----------------

__global__ __launch_bounds__(256) void mlp2pool(
    const uint* __restrict__ z1p,
    const float* __restrict__ W2a, const float* __restrict__ b2a,
    const float* __restrict__ W2b, const float* __restrict__ b2b,
    const int* __restrict__ batch,
    float* __restrict__ sums, float* __restrict__ counts, int N)
{
    __shared__ float Wa[64 * 64];
    __shared__ float Wb[64 * 64];
    for (int i = threadIdx.x; i < 64 * 64; i += 256) {
        Wa[i] = W2a[i];
        Wb[i] = W2b[i];
    }
    __syncthreads();

    int lane = threadIdx.x & 63;
    int wv = blockIdx.x * 4 + (threadIdx.x >> 6);
    int i0 = wv * 4;
    if (i0 >= N) return;
    float ba = b2a[lane], bb = b2b[lane];

    // zl[n]: feat=lane of node i0+n (unpack from packed f16 row)
    float zl[4];
#pragma unroll
    for (int n = 0; n < 4; n++) {
        uint d = z1p[(size_t)(i0 + n) * 32 + (lane >> 1)];
        __half2 h = *(__half2*)&d;
        zl[n] = (lane & 1) ? __high2float(h) : __low2float(h);
    }

    float t[4], o[4];
#pragma unroll
    for (int n = 0; n < 4; n++) t[n] = ba;
#pragma unroll
    for (int k = 0; k < 64; k++) {
        float wa = Wa[k * 64 + lane];
#pragma unroll
        for (int n = 0; n < 4; n++) t[n] += rlane(zl[n], k) * wa;
    }
#pragma unroll
    for (int n = 0; n < 4; n++) { t[n] = fmaxf(t[n], 0.f); o[n] = bb; }
#pragma unroll
    for (int k = 0; k < 64; k++) {
        float wb = Wb[k * 64 + lane];
#pragma unroll
        for (int n = 0; n < 4; n++) o[n] += rlane(t[n], k) * wb;
    }

    int gcur = batch[i0]; float ps = 0.f; int cnt = 0;
#pragma unroll
    for (int n = 0; n < 4; n++) {
        float h2 = fmaxf(o[n], 0.f);           // outer relu L2
        int gi = batch[i0 + n];
        if (gi != gcur) {
            atomicAdd(&sums[gcur * 64 + lane], ps);
            if (lane == 0) atomicAdd(&counts[gcur], (float)cnt);
            gcur = gi; ps = 0.f; cnt = 0;
        }
        ps += h2; cnt++;
    }
    atomicAdd(&sums[gcur * 64 + lane], ps);
    if (lane == 0) atomicAdd(&counts[gcur], (float)cnt);
}

__global__ __launch_bounds__(256) void gin_final(
    const float* __restrict__ sums, const float* __restrict__ counts,
    const float* __restrict__ Wlin, const float* __restrict__ blin,
    float* __restrict__ out, int G)
{
    int lane = threadIdx.x & 63;
    int g    = blockIdx.x * 4 + (threadIdx.x >> 6);
    if (g < G) {
        float v = sums[g * 64 + lane] * Wlin[lane];
#pragma unroll
        for (int off = 32; off > 0; off >>= 1) v += __shfl_down(v, off, 64);
        if (lane == 0) out[g] = v / fmaxf(counts[g], 1.0f) + blin[0];
    }
}

extern "C" void kernel_launch(void* const* d_in, const int* in_sizes, int n_in,
                              void* d_out, int out_size, void* d_ws, size_t ws_size,
                              hipStream_t stream) {
    const float* x    = (const float*)d_in[0];
    const float* pos  = (const float*)d_in[1];
    const int*   ei   = (const int*)d_in[2];
    const int*   batch= (const int*)d_in[3];
    const float* W1a  = (const float*)d_in[4];
    const float* b1a  = (const float*)d_in[5];
    const float* W1b  = (const float*)d_in[6];
    const float* b1b  = (const float*)d_in[7];
    const float* W2a  = (const float*)d_in[8];
    const float* b2a  = (const float*)d_in[9];
    const float* W2b  = (const float*)d_in[10];
    const float* b2b  = (const float*)d_in[11];
    const float* Wlin = (const float*)d_in[12];
    const float* blin = (const float*)d_in[13];
    float* out = (float*)d_out;

    const int N = in_sizes[0] / 11;     // 50000
    const int E = in_sizes[2] / 2;      // 800000
    const int G = out_size;             // 2500

    const int* src = ei;
    const int* dst = ei + E;
    const int NB = (N + 255) / 256;

    // Workspace: [deg|sums|counts](memset) |offs|cursor|bsum|ssrc|h1p|z0/z1p(union)
    char* ws = (char*)d_ws;
    size_t o = 0;
    int*   deg    = (int*)(ws + o);   o += (size_t)N * 4;
    float* sums   = (float*)(ws + o); o += (size_t)G * 64 * 4;
    float* counts = (float*)(ws + o); o += (((size_t)G + 63) & ~(size_t)63) * 4;
    size_t zero_bytes = o;
    int*   offs   = (int*)(ws + o);   o += (size_t)N * 4;
    int*   cursor = (int*)(ws + o);   o += (size_t)N * 4;
    int*   bsum   = (int*)(ws + o);   o += 256 * 4;
    int*   ssrc   = (int*)(ws + o);   o += (size_t)E * 4;
    o = (o + 255) & ~(size_t)255;
    uint*  h1p    = (uint*)(ws + o);  o += (size_t)N * 32 * 4;
    float* z0     = (float*)(ws + o); // N*16 f32 (2.4 MB), dead after mlp1
    uint*  z1p    = (uint*)(ws + o);  // N*32 dwords (6.4 MB), aliases z0

    hipMemsetAsync(ws, 0, zero_bytes, stream);

    count_deg<<<(E + 255) / 256, 256, 0, stream>>>(dst, deg, E);
    scan1<<<NB, 256, 0, stream>>>(deg, offs, bsum, N);
    scan2<<<1, 256, 0, stream>>>(bsum, NB);
    scan3<<<NB, 256, 0, stream>>>(offs, bsum, cursor, N);
    fill_csr<<<(E + 255) / 256, 256, 0, stream>>>(src, dst, cursor, ssrc, E);

    gather1<<<(N + 3) / 4, 256, 0, stream>>>(x, pos, offs, deg, ssrc, z0, N);
    mlp1<<<(N + 15) / 16, 256, 0, stream>>>(z0, W1a, b1a, W1b, b1b, h1p, N);
    gather2<<<(N + 3) / 4, 256, 0, stream>>>(h1p, offs, deg, ssrc, z1p, N);
    mlp2pool<<<(N + 15) / 16, 256, 0, stream>>>(
        z1p, W2a, b2a, W2b, b2b, batch, sums, counts, N);

    gin_final<<<(G + 3) / 4, 256, 0, stream>>>(
        sums, counts, Wlin, blin, out, G);
}